// Round 11
// baseline (509.208 us; speedup 1.0000x reference)
//
#include <hip/hip_runtime.h>
#include <math.h>

#define BB 64
#define RR 6912
#define II 8
#define CC 10
#define OO 16
#define RPB 64          // routes per block (chunk)
#define NCH 108         // RR / RPB  (blocks per class)
#define NIT 8           // route iters; each covers 8 routes (4 waves x 2 rr)
#define GRID (CC * NCH) // 1080
#define LDSF 4608       // 18432 B: W tile (16 KB) / merge buf (18 KB) / zb (256 B)

typedef _Float16 h2 __attribute__((ext_vector_type(2)));
typedef __fp16  g2 __attribute__((ext_vector_type(2)));
union HV { int4 v; h2 h[4]; };

static __device__ __forceinline__ h2 pkrtz(float a, float b) {
    g2 r = __builtin_amdgcn_cvt_pkrtz(a, b);
    return __builtin_bit_cast(h2, r);
}

// ---------------- pass kernel ----------------
// MODE 0: converts own W tile f32->f16 (LDS + writeback to wh), plain prior sum.
// MODE 1/2: stages W tile from wh; softmax-weighted sum (no max-subtraction:
// |logit| small, validated R5-R8). Main loop is barrier-free; x read directly
// from original [b][r][8] f32 layout, converted inline with cvt_pkrtz.
// Epilogue: block partial -> pacc/pz, then last-block-per-class combine+squash.
template <int MODE>
__global__ __launch_bounds__(256, 4) void pass_kernel(
    const float* __restrict__ x, const float4* __restrict__ w4,
    int4* __restrict__ wh4, const float* __restrict__ ov_in,
    float* __restrict__ pacc, float* __restrict__ pz,
    int* __restrict__ cnt, float* __restrict__ outw)
{
    __shared__ __align__(16) float lds[LDSF];
    __shared__ int lastflag;
    int4* wlds = (int4*)lds;           // 1024 int4 = 64 routes x 16 o x (8 i f16)

    const int bid = blockIdx.x;
    const int c = bid / NCH;
    const int chunk = bid - c * NCH;
    const int t = threadIdx.x;
    const int wv = t >> 6;
    const int lane = t & 63;
    const int rr = lane >> 5;
    const int bg = lane & 31;

    // ---- stage W tile (f16 [rl][o][i], 16 KB) ----
    if (MODE == 0) {
        // convert own 64 routes from f32 [r][i][o]; keep in LDS + write to wh
        _Float16* wl = (_Float16*)lds;
        const int rp = t >> 5, i = (t >> 2) & 7, o0 = (t & 3) * 4;
        const float4* src = w4 + (size_t)(c * RR + chunk * RPB) * 32;
#pragma unroll 1
        for (int k = 0; k < 8; ++k) {
            const float4 v = src[k * 256 + t];
            const int rl8 = k * 8 + rp;
            wl[(rl8 * 16 + o0 + 0) * 8 + i] = (_Float16)v.x;
            wl[(rl8 * 16 + o0 + 1) * 8 + i] = (_Float16)v.y;
            wl[(rl8 * 16 + o0 + 2) * 8 + i] = (_Float16)v.z;
            wl[(rl8 * 16 + o0 + 3) * 8 + i] = (_Float16)v.w;
        }
        __syncthreads();
        int4* dst = wh4 + (size_t)bid * 1024;
#pragma unroll
        for (int j = 0; j < 4; ++j) dst[j * 256 + t] = wlds[j * 256 + t];
    } else {
        const int4* src = wh4 + (size_t)bid * 1024;
#pragma unroll
        for (int k = 0; k < 4; ++k) wlds[k * 256 + t] = src[k * 256 + t];
    }

    float ov0[OO], ov1[OO];
    if (MODE != 0) {
        const float4* opa = (const float4*)(ov_in + ((size_t)c * BB + bg) * OO);
        const float4* opb = (const float4*)(ov_in + ((size_t)c * BB + bg + 32) * OO);
#pragma unroll
        for (int q = 0; q < 4; ++q) {
            float4 va = opa[q], vb = opb[q];
            ov0[q*4+0]=va.x; ov0[q*4+1]=va.y; ov0[q*4+2]=va.z; ov0[q*4+3]=va.w;
            ov1[q*4+0]=vb.x; ov1[q*4+1]=vb.y; ov1[q*4+2]=vb.z; ov1[q*4+3]=vb.w;
        }
    }

    __syncthreads();   // W tile ready; barrier-free main loop follows

    float acc0[OO], acc1[OO];
#pragma unroll
    for (int o = 0; o < OO; ++o) { acc0[o] = 0.f; acc1[o] = 0.f; }
    float Z0 = 0.f, Z1 = 0.f;

#pragma unroll 1
    for (int it = 0; it < NIT; ++it) {
        const int rl = it * 8 + wv * 2 + rr;
        const int r  = chunk * RPB + rl;
        const float4* xp0 = (const float4*)(x + ((size_t)bg * RR + r) * II);
        const float4* xp1 = (const float4*)(x + ((size_t)(bg + 32) * RR + r) * II);
        const float4 a0 = xp0[0], a1 = xp0[1];
        const float4 c0 = xp1[0], c1 = xp1[1];
        HV xa, xb;
        xa.h[0] = pkrtz(a0.x, a0.y);
        xa.h[1] = pkrtz(a0.z, a0.w);
        xa.h[2] = pkrtz(a1.x, a1.y);
        xa.h[3] = pkrtz(a1.z, a1.w);
        xb.h[0] = pkrtz(c0.x, c0.y);
        xb.h[1] = pkrtz(c0.z, c0.w);
        xb.h[2] = pkrtz(c1.x, c1.y);
        xb.h[3] = pkrtz(c1.z, c1.w);

        float p0[OO], p1[OO];
#pragma unroll
        for (int o = 0; o < OO; ++o) {
            HV wq; wq.v = wlds[rl * 16 + o];
            float a = __builtin_amdgcn_fdot2(xa.h[0], wq.h[0],
                        (MODE == 0) ? acc0[o] : 0.f, false);
            a = __builtin_amdgcn_fdot2(xa.h[1], wq.h[1], a, false);
            a = __builtin_amdgcn_fdot2(xa.h[2], wq.h[2], a, false);
            a = __builtin_amdgcn_fdot2(xa.h[3], wq.h[3], a, false);
            float b2 = __builtin_amdgcn_fdot2(xb.h[0], wq.h[0],
                        (MODE == 0) ? acc1[o] : 0.f, false);
            b2 = __builtin_amdgcn_fdot2(xb.h[1], wq.h[1], b2, false);
            b2 = __builtin_amdgcn_fdot2(xb.h[2], wq.h[2], b2, false);
            b2 = __builtin_amdgcn_fdot2(xb.h[3], wq.h[3], b2, false);
            if (MODE == 0) { acc0[o] = a; acc1[o] = b2; }
            else           { p0[o] = a;   p1[o] = b2; }
        }

        if (MODE != 0) {
            float d0 = 0.f, d1 = 0.f;
#pragma unroll
            for (int o = 0; o < OO; ++o) { d0 = fmaf(p0[o], ov0[o], d0); d1 = fmaf(p1[o], ov1[o], d1); }
            const float e0 = __expf(d0), e1 = __expf(d1);
            Z0 += e0; Z1 += e1;
#pragma unroll
            for (int o = 0; o < OO; ++o) { acc0[o] = fmaf(e0, p0[o], acc0[o]); acc1[o] = fmaf(e1, p1[o], acc1[o]); }
        }
    }

    // reduce across rr (lane ^ 32): sums the two routes of this wave
#pragma unroll
    for (int o = 0; o < OO; ++o) {
        acc0[o] += __shfl_xor(acc0[o], 32);
        acc1[o] += __shfl_xor(acc1[o], 32);
    }
    if (MODE != 0) { Z0 += __shfl_xor(Z0, 32); Z1 += __shfl_xor(Z1, 32); }

    __syncthreads();   // done reading W tile; reuse LDS for merge
    if (rr == 0) {
        float* s = lds + (wv * 32 + bg) * 36;
#pragma unroll
        for (int o = 0; o < OO; ++o) { s[o] = acc0[o]; s[16 + o] = acc1[o]; }
        s[32] = Z0; s[33] = Z1;
    }
    __syncthreads();

    // block partial -> global: thread t -> (b = t>>2, o-quad q = t&3)
    {
        const int b = t >> 2, q = t & 3;
        const int k = b >> 5, bgf = b & 31;
        float4 sum = make_float4(0.f, 0.f, 0.f, 0.f);
#pragma unroll
        for (int w2 = 0; w2 < 4; ++w2) {
            const float4 v = *(const float4*)(lds + (w2 * 32 + bgf) * 36 + k * 16 + q * 4);
            sum.x += v.x; sum.y += v.y; sum.z += v.z; sum.w += v.w;
        }
        *(float4*)(pacc + ((size_t)bid * BB + b) * OO + q * 4) = sum;
        if (MODE != 0 && q == 0) {
            float z = 0.f;
#pragma unroll
            for (int w2 = 0; w2 < 4; ++w2) z += lds[(w2 * 32 + bgf) * 36 + 32 + k];
            pz[(size_t)bid * BB + b] = z;
        }
    }

    // ---- last-block-per-class combine + squash ----
    __threadfence();
    __syncthreads();
    if (t == 0) lastflag = (atomicAdd(cnt + c, 1) == NCH - 1) ? 1 : 0;
    __syncthreads();
    if (lastflag) {
        __threadfence();   // acquire: other blocks' partials now visible
        const int b = t >> 2, q = t & 3;
        float s0 = 0.f, s1 = 0.f, s2 = 0.f, s3 = 0.f, z = 0.f;
#pragma unroll 4
        for (int p = 0; p < NCH; ++p) {
            const float4 v = *(const float4*)(pacc + ((size_t)(c * NCH + p) * BB + b) * OO + q * 4);
            s0 += v.x; s1 += v.y; s2 += v.z; s3 += v.w;
            if (MODE != 0) { if (q == 0) z += pz[(size_t)(c * NCH + p) * BB + b]; }
        }
        if (MODE != 0) {
            float* zb = lds;   // 64 floats; LDS free after merge
            if (q == 0) zb[b] = z;
            __syncthreads();
            const float inv = 1.0f / zb[b];
            s0 *= inv; s1 *= inv; s2 *= inv; s3 *= inv;
        } else {
            const float inv = 1.0f / RR;
            s0 *= inv; s1 *= inv; s2 *= inv; s3 *= inv;
        }
        float sq = s0 * s0 + s1 * s1 + s2 * s2 + s3 * s3;
        sq += __shfl_xor(sq, 1);
        sq += __shfl_xor(sq, 2);
        const float f = sqrtf(sq) / (1.f + sq);
        float4 val = make_float4(s0 * f, s1 * f, s2 * f, s3 * f);
        if (MODE == 1) {
            const float4 o4 = *(const float4*)(ov_in + ((size_t)c * BB + b) * OO + q * 4);
            val.x += o4.x; val.y += o4.y; val.z += o4.z; val.w += o4.w;
        }
        *(float4*)(outw + ((size_t)c * BB + b) * OO + q * 4) = val;
    }
}

extern "C" void kernel_launch(void* const* d_in, const int* in_sizes, int n_in,
                              void* d_out, int out_size, void* d_ws, size_t ws_size,
                              hipStream_t stream)
{
    const float* x = (const float*)d_in[0];
    const float4* w4 = (const float4*)d_in[1];
    float* out = (float*)d_out;

    float* ws = (float*)d_ws;
    float* wh     = ws;                                   // CC*RR*128 f16 = CC*RR*64 f32 slots
    float* pacc   = wh + (size_t)CC * RR * 64;            // GRID*BB*OO
    float* pz     = pacc + (size_t)GRID * BB * OO;        // GRID*BB
    float* out0   = pz + (size_t)GRID * BB;               // CC*BB*OO
    float* outsum = out0 + CC * BB * OO;                  // CC*BB*OO
    int*   cnt    = (int*)(outsum + CC * BB * OO);        // 3*CC ints

    int4* wh4 = (int4*)wh;

    (void)hipMemsetAsync(cnt, 0, 3 * CC * sizeof(int), stream);

    const dim3 gp(GRID), bp(256);
    pass_kernel<0><<<gp, bp, 0, stream>>>(x, w4, wh4, nullptr, pacc, pz, cnt,          out0);
    pass_kernel<1><<<gp, bp, 0, stream>>>(x, w4, wh4, out0,    pacc, pz, cnt + CC,     outsum);
    pass_kernel<2><<<gp, bp, 0, stream>>>(x, w4, wh4, outsum,  pacc, pz, cnt + 2 * CC, out);
}

// Round 12
// 475.133 us; speedup vs baseline: 1.0717x; 1.0717x over previous
//
#include <hip/hip_runtime.h>
#include <math.h>

#define BB 64
#define RR 6912
#define II 8
#define CC 10
#define OO 16
#define RPB 64          // routes per block (chunk)
#define NCH 108         // RR / RPB  (blocks per class)
#define NIT 8           // route iters; each covers 8 routes (4 waves x 2 rr)
#define GRID (CC * NCH) // 1080
#define LDSF 4608       // 18432 B: W tile (16 KB) / merge buf (18 KB) / zb (256 B)

typedef _Float16 h2 __attribute__((ext_vector_type(2)));
union HV { int4 v; h2 h[4]; };

// ---------------- transpose+cvt kernel: x[B][R][8] f32 -> xth[R][B][8] f16 ----------------
__global__ __launch_bounds__(256) void transpose_cvt_kernel(
    const float* __restrict__ x, int4* __restrict__ xth4)
{
    __shared__ float4 lds4[64 * 34];   // [rl][bl*2+h], stride 34 breaks banks
    const int rblk = blockIdx.x >> 2;
    const int bblk = blockIdx.x & 3;
    const int r0 = rblk * 64, b0 = bblk * 16;
    const int t = threadIdx.x;
    {
        const int rl = t & 63;
        const int bl0 = t >> 6;
#pragma unroll
        for (int kb = 0; kb < 4; ++kb) {
            const int bl = kb * 4 + bl0;
            const float4* src = (const float4*)(x + ((size_t)(b0 + bl) * RR + (r0 + rl)) * II);
            lds4[rl * 34 + bl * 2 + 0] = src[0];
            lds4[rl * 34 + bl * 2 + 1] = src[1];
        }
    }
    __syncthreads();
    {
        const int bl = t & 15;
        const int rw0 = t >> 4;
#pragma unroll
        for (int kr = 0; kr < 4; ++kr) {
            const int rw = kr * 16 + rw0;
            float4 a = lds4[rw * 34 + bl * 2 + 0];
            float4 bq = lds4[rw * 34 + bl * 2 + 1];
            HV u;
            u.h[0] = h2{(_Float16)a.x,  (_Float16)a.y};
            u.h[1] = h2{(_Float16)a.z,  (_Float16)a.w};
            u.h[2] = h2{(_Float16)bq.x, (_Float16)bq.y};
            u.h[3] = h2{(_Float16)bq.z, (_Float16)bq.w};
            xth4[(size_t)(r0 + rw) * BB + (b0 + bl)] = u.v;
        }
    }
}

// ---------------- pass kernel ----------------
// MODE 0: converts own 64-route W tile f32->f16 in LDS (+ writeback to wh).
// MODE 1/2: stages W tile from wh. Main loop barrier-free (R8-proven): wave wv
// covers routes it*8+wv*2+rr; thread handles batches bg, bg+32 via coalesced
// f16 xth loads; dot2 f16 compute, f32 accumulate; no max-subtraction.
// Epilogue: block partial -> pacc/pz, then last-block-per-class combine+squash.
template <int MODE>
__global__ __launch_bounds__(256, 4) void pass_kernel(
    const int4* __restrict__ xth4, const float4* __restrict__ w4,
    int4* __restrict__ wh4, const float* __restrict__ ov_in,
    float* __restrict__ pacc, float* __restrict__ pz,
    int* __restrict__ cnt, float* __restrict__ outw)
{
    __shared__ __align__(16) float lds[LDSF];
    __shared__ int lastflag;
    int4* wlds = (int4*)lds;           // 1024 int4 = 64 routes x 16 o x (8 i f16)

    const int bid = blockIdx.x;
    const int c = bid / NCH;
    const int chunk = bid - c * NCH;
    const int t = threadIdx.x;
    const int wv = t >> 6;
    const int lane = t & 63;
    const int rr = lane >> 5;
    const int bg = lane & 31;

    // ---- stage W tile (f16 [rl][o][i], 16 KB) ----
    if (MODE == 0) {
        _Float16* wl = (_Float16*)lds;
        const int rp = t >> 5, i = (t >> 2) & 7, o0 = (t & 3) * 4;
        const float4* src = w4 + (size_t)(c * RR + chunk * RPB) * 32;
#pragma unroll 1
        for (int k = 0; k < 8; ++k) {
            const float4 v = src[k * 256 + t];
            const int rl8 = k * 8 + rp;
            wl[(rl8 * 16 + o0 + 0) * 8 + i] = (_Float16)v.x;
            wl[(rl8 * 16 + o0 + 1) * 8 + i] = (_Float16)v.y;
            wl[(rl8 * 16 + o0 + 2) * 8 + i] = (_Float16)v.z;
            wl[(rl8 * 16 + o0 + 3) * 8 + i] = (_Float16)v.w;
        }
        __syncthreads();
        int4* dst = wh4 + (size_t)bid * 1024;
#pragma unroll
        for (int j = 0; j < 4; ++j) dst[j * 256 + t] = wlds[j * 256 + t];
    } else {
        const int4* src = wh4 + (size_t)bid * 1024;
#pragma unroll
        for (int k = 0; k < 4; ++k) wlds[k * 256 + t] = src[k * 256 + t];
    }

    float ov0[OO], ov1[OO];
    if (MODE != 0) {
        const float4* opa = (const float4*)(ov_in + ((size_t)c * BB + bg) * OO);
        const float4* opb = (const float4*)(ov_in + ((size_t)c * BB + bg + 32) * OO);
#pragma unroll
        for (int q = 0; q < 4; ++q) {
            float4 va = opa[q], vb = opb[q];
            ov0[q*4+0]=va.x; ov0[q*4+1]=va.y; ov0[q*4+2]=va.z; ov0[q*4+3]=va.w;
            ov1[q*4+0]=vb.x; ov1[q*4+1]=vb.y; ov1[q*4+2]=vb.z; ov1[q*4+3]=vb.w;
        }
    }

    __syncthreads();   // W tile ready; barrier-free main loop follows

    float acc0[OO], acc1[OO];
#pragma unroll
    for (int o = 0; o < OO; ++o) { acc0[o] = 0.f; acc1[o] = 0.f; }
    float Z0 = 0.f, Z1 = 0.f;

#pragma unroll 1
    for (int it = 0; it < NIT; ++it) {
        const int rl = it * 8 + wv * 2 + rr;
        const int r  = chunk * RPB + rl;
        HV xa, xb;
        xa.v = xth4[(size_t)r * BB + bg];
        xb.v = xth4[(size_t)r * BB + bg + 32];

        float p0[OO], p1[OO];
#pragma unroll
        for (int o = 0; o < OO; ++o) {
            HV wq; wq.v = wlds[rl * 16 + o];
            float a = __builtin_amdgcn_fdot2(xa.h[0], wq.h[0],
                        (MODE == 0) ? acc0[o] : 0.f, false);
            a = __builtin_amdgcn_fdot2(xa.h[1], wq.h[1], a, false);
            a = __builtin_amdgcn_fdot2(xa.h[2], wq.h[2], a, false);
            a = __builtin_amdgcn_fdot2(xa.h[3], wq.h[3], a, false);
            float b2 = __builtin_amdgcn_fdot2(xb.h[0], wq.h[0],
                        (MODE == 0) ? acc1[o] : 0.f, false);
            b2 = __builtin_amdgcn_fdot2(xb.h[1], wq.h[1], b2, false);
            b2 = __builtin_amdgcn_fdot2(xb.h[2], wq.h[2], b2, false);
            b2 = __builtin_amdgcn_fdot2(xb.h[3], wq.h[3], b2, false);
            if (MODE == 0) { acc0[o] = a; acc1[o] = b2; }
            else           { p0[o] = a;   p1[o] = b2; }
        }

        if (MODE != 0) {
            float d0 = 0.f, d1 = 0.f;
#pragma unroll
            for (int o = 0; o < OO; ++o) { d0 = fmaf(p0[o], ov0[o], d0); d1 = fmaf(p1[o], ov1[o], d1); }
            const float e0 = __expf(d0), e1 = __expf(d1);
            Z0 += e0; Z1 += e1;
#pragma unroll
            for (int o = 0; o < OO; ++o) { acc0[o] = fmaf(e0, p0[o], acc0[o]); acc1[o] = fmaf(e1, p1[o], acc1[o]); }
        }
    }

    // reduce across rr (lane ^ 32)
#pragma unroll
    for (int o = 0; o < OO; ++o) {
        acc0[o] += __shfl_xor(acc0[o], 32);
        acc1[o] += __shfl_xor(acc1[o], 32);
    }
    if (MODE != 0) { Z0 += __shfl_xor(Z0, 32); Z1 += __shfl_xor(Z1, 32); }

    __syncthreads();   // done reading W tile; reuse LDS for merge
    if (rr == 0) {
        float* s = lds + (wv * 32 + bg) * 36;
#pragma unroll
        for (int o = 0; o < OO; ++o) { s[o] = acc0[o]; s[16 + o] = acc1[o]; }
        s[32] = Z0; s[33] = Z1;
    }
    __syncthreads();

    // block partial -> global: thread t -> (b = t>>2, o-quad q = t&3)
    {
        const int b = t >> 2, q = t & 3;
        const int k = b >> 5, bgf = b & 31;
        float4 sum = make_float4(0.f, 0.f, 0.f, 0.f);
#pragma unroll
        for (int w2 = 0; w2 < 4; ++w2) {
            const float4 v = *(const float4*)(lds + (w2 * 32 + bgf) * 36 + k * 16 + q * 4);
            sum.x += v.x; sum.y += v.y; sum.z += v.z; sum.w += v.w;
        }
        *(float4*)(pacc + ((size_t)bid * BB + b) * OO + q * 4) = sum;
        if (MODE != 0 && q == 0) {
            float z = 0.f;
#pragma unroll
            for (int w2 = 0; w2 < 4; ++w2) z += lds[(w2 * 32 + bgf) * 36 + 32 + k];
            pz[(size_t)bid * BB + b] = z;
        }
    }

    // ---- last-block-per-class combine + squash (R11-proven) ----
    __threadfence();
    __syncthreads();
    if (t == 0) lastflag = (atomicAdd(cnt + c, 1) == NCH - 1) ? 1 : 0;
    __syncthreads();
    if (lastflag) {
        __threadfence();   // acquire: other blocks' partials now visible
        const int b = t >> 2, q = t & 3;
        float s0 = 0.f, s1 = 0.f, s2 = 0.f, s3 = 0.f, z = 0.f;
#pragma unroll 4
        for (int p = 0; p < NCH; ++p) {
            const float4 v = *(const float4*)(pacc + ((size_t)(c * NCH + p) * BB + b) * OO + q * 4);
            s0 += v.x; s1 += v.y; s2 += v.z; s3 += v.w;
            if (MODE != 0) { if (q == 0) z += pz[(size_t)(c * NCH + p) * BB + b]; }
        }
        if (MODE != 0) {
            float* zb = lds;
            if (q == 0) zb[b] = z;
            __syncthreads();
            const float inv = 1.0f / zb[b];
            s0 *= inv; s1 *= inv; s2 *= inv; s3 *= inv;
        } else {
            const float inv = 1.0f / RR;
            s0 *= inv; s1 *= inv; s2 *= inv; s3 *= inv;
        }
        float sq = s0 * s0 + s1 * s1 + s2 * s2 + s3 * s3;
        sq += __shfl_xor(sq, 1);
        sq += __shfl_xor(sq, 2);
        const float f = sqrtf(sq) / (1.f + sq);
        float4 val = make_float4(s0 * f, s1 * f, s2 * f, s3 * f);
        if (MODE == 1) {
            const float4 o4 = *(const float4*)(ov_in + ((size_t)c * BB + b) * OO + q * 4);
            val.x += o4.x; val.y += o4.y; val.z += o4.z; val.w += o4.w;
        }
        *(float4*)(outw + ((size_t)c * BB + b) * OO + q * 4) = val;
    }
}

extern "C" void kernel_launch(void* const* d_in, const int* in_sizes, int n_in,
                              void* d_out, int out_size, void* d_ws, size_t ws_size,
                              hipStream_t stream)
{
    const float* x = (const float*)d_in[0];
    const float4* w4 = (const float4*)d_in[1];
    float* out = (float*)d_out;

    float* ws = (float*)d_ws;
    float* xth    = ws;                                   // RR*BB*4 f32 slots (f16 x8)
    float* wh     = xth + (size_t)RR * BB * 4;            // CC*RR*64 f32 slots (f16 x128)
    float* pacc   = wh + (size_t)CC * RR * 64;            // GRID*BB*OO
    float* pz     = pacc + (size_t)GRID * BB * OO;        // GRID*BB
    float* out0   = pz + (size_t)GRID * BB;               // CC*BB*OO
    float* outsum = out0 + CC * BB * OO;                  // CC*BB*OO
    int*   cnt    = (int*)(outsum + CC * BB * OO);        // 3*CC ints

    int4* xth4 = (int4*)xth;
    int4* wh4  = (int4*)wh;

    (void)hipMemsetAsync(cnt, 0, 3 * CC * sizeof(int), stream);

    transpose_cvt_kernel<<<dim3((RR / 64) * 4), dim3(256), 0, stream>>>(x, xth4);

    const dim3 gp(GRID), bp(256);
    pass_kernel<0><<<gp, bp, 0, stream>>>(xth4, w4, wh4, nullptr, pacc, pz, cnt,          out0);
    pass_kernel<1><<<gp, bp, 0, stream>>>(xth4, w4, wh4, out0,    pacc, pz, cnt + CC,     outsum);
    pass_kernel<2><<<gp, bp, 0, stream>>>(xth4, w4, wh4, outsum,  pacc, pz, cnt + 2 * CC, out);
}